// Round 7
// baseline (144.872 us; speedup 1.0000x reference)
//
#include <hip/hip_runtime.h>
#include <hip/hip_bf16.h>
#include <math.h>

// FM model: out[s] = sigmoid(0.5*sum_e((sum_f v[s,f,e])^2 - sum_f v[s,f,e]^2)
//                           + sum_f linear[s,f])
// user[16384,20,33], ctx[16384,10,33], doc[16384,30,33]; v=[:,:,0:32], linear=[:,:,32]
//
// R5 post-mortem: coalescing fixed (FETCH ideal) but still latency-bound:
// 8192 one-shot blocks churn (3.2 residency rounds), each a serial
// stage->stall->compute; occupancy 33% (half the LDS cap), VALU 9.5%.
// R6: persistent pipelined blocks. 2048 blocks (8/CU, ALL resident, no churn)
// x 4 pairs each. Register-buffered pipeline: issue pair i+1's 9 dwordx4
// loads BEFORE computing pair i from LDS (latency hides under compute +
// 15 other waves/CU), then barrier -> regs->LDS -> barrier. LDS stays
// 15.84KB/block -> sustained 16 waves/CU.

#define NS 16384
#define PPB 4  // pairs per block; 8192 pairs / 2048 blocks

__global__ __launch_bounds__(128) void fm_kernel(
    const float* __restrict__ user,
    const float* __restrict__ ctx,
    const float* __restrict__ doc,
    float* __restrict__ out) {
  // pair blob: user-pair 1320 + ctx-pair 660 + doc-pair 1980 = 3960 floats
  __shared__ float smem[3960];

  const int tid = threadIdx.x;
  const int pair0 = blockIdx.x * PPB;

  float4* su = (float4*)smem;           // 330 f4
  float4* sc = (float4*)(smem + 1320);  // 165 f4
  float4* sd = (float4*)(smem + 1980);  // 495 f4

  // staging predicates (loop-invariant)
  const bool pu = (256 + tid) < 330;   // user tail: 74
  const bool pc = (128 + tid) < 165;   // ctx  tail: 37
  const bool pd = (384 + tid) < 495;   // doc  tail: 111

  // register staging buffer (9 float4 = 36 VGPR)
  float4 r0, r1, r2, r3, r4, r5, r6, r7, r8;

  auto LOAD = [&](int pair) {
    const float4* gu = (const float4*)(user + (size_t)(2 * pair) * 660);
    const float4* gc = (const float4*)(ctx  + (size_t)(2 * pair) * 330);
    const float4* gd = (const float4*)(doc  + (size_t)(2 * pair) * 990);
    r0 = gu[tid];
    r1 = gu[128 + tid];
    if (pu) r2 = gu[256 + tid];
    r3 = gc[tid];
    if (pc) r4 = gc[128 + tid];
    r5 = gd[tid];
    r6 = gd[128 + tid];
    r7 = gd[256 + tid];
    if (pd) r8 = gd[384 + tid];
  };
  auto STORE = [&]() {
    su[tid] = r0;
    su[128 + tid] = r1;
    if (pu) su[256 + tid] = r2;
    sc[tid] = r3;
    if (pc) sc[128 + tid] = r4;
    sd[tid] = r5;
    sd[128 + tid] = r6;
    sd[256 + tid] = r7;
    if (pd) sd[384 + tid] = r8;
  };

  // prologue: stage pair0
  LOAD(pair0);
  STORE();
  __syncthreads();

  // compute-lane mapping: wave w owns sample 2*pair+w
  const int w = tid >> 6;   // wave id
  const int l = tid & 63;   // lane
  const int h = l >> 5;     // field-half (0: user+ctx, 1: doc)
  const int e = l & 31;     // latent element

  const float* mu = smem + w * 660;
  const float* mc = smem + 1320 + w * 330;
  const float* md = smem + 1980 + w * 990;
  const float* p1 = (h ? md : mu) + e;
  const float* p2 = (h ? (md + 660) : mc) + e;

  for (int it = 0; it < PPB; ++it) {
    const bool more = (it + 1 < PPB);
    if (more) LOAD(pair0 + it + 1);  // in flight during compute below

    float sv = 0.f, sv2 = 0.f;
#pragma unroll
    for (int f = 0; f < 20; ++f) {
      float x = p1[f * 33];
      sv += x; sv2 = fmaf(x, x, sv2);
    }
#pragma unroll
    for (int f = 0; f < 10; ++f) {
      float x = p2[f * 33];
      sv += x; sv2 = fmaf(x, x, sv2);
    }

    float lin = 0.f;
    if (h == 0) {
      if (e < 20)      lin = mu[e * 33 + 32];
      else if (e < 30) lin = mc[(e - 20) * 33 + 32];
    } else {
      if (e < 30) lin = md[e * 33 + 32];
    }

    // merge field-halves, then reduce the 32 elements
    float svT  = sv  + __shfl_xor(sv,  32, 64);
    float sv2T = sv2 + __shfl_xor(sv2, 32, 64);
    float linT = lin + __shfl_xor(lin, 32, 64);
    float part = fmaf(svT, svT, -sv2T);
#pragma unroll
    for (int m = 16; m > 0; m >>= 1) {
      part += __shfl_xor(part, m, 64);
      linT += __shfl_xor(linT, m, 64);
    }
    if (l == 0) {
      float logit = fmaf(0.5f, part, linT);
      out[2 * (pair0 + it) + w] = 1.f / (1.f + expf(-logit));
    }

    if (more) {
      __syncthreads();   // all waves done reading pair it
      STORE();           // vmcnt(0) waited here, after compute covered latency
      __syncthreads();   // staged data visible before next compute
    }
  }
}

extern "C" void kernel_launch(void* const* d_in, const int* in_sizes, int n_in,
                              void* d_out, int out_size, void* d_ws, size_t ws_size,
                              hipStream_t stream) {
  const float* user = (const float*)d_in[0];
  const float* ctx  = (const float*)d_in[1];
  const float* doc  = (const float*)d_in[2];
  float* out = (float*)d_out;

  // 2048 persistent-ish blocks x 4 pairs = 8192 pairs = 16384 samples
  dim3 block(128);
  dim3 grid(NS / 2 / PPB);
  fm_kernel<<<grid, block, 0, stream>>>(user, ctx, doc, out);
}